// Round 2
// baseline (103388.940 us; speedup 1.0000x reference)
//
#include <hip/hip_runtime.h>
#include <stdint.h>

// BetterMCMC: bit-exact replication of the JAX reference MH chain.
// RNG mode: threefry_partitionable = True (JAX >= 0.4.36 default).
//   - split(key, n)[i] = cipher(key, (0,i))  (both output words, stacked)
//   - random_bits(key, 32, shape)[i] = w1 ^ w2 of cipher(key, (0,i))   <-- R2 fix
// Fresh chain-weight sum: sequential left-to-right fp32 (XLA-CPU loop-emitter hypothesis).

#define NW 4096
#define NSTEPS 2559
#define NTHREADS 1024
#define NWAVES 16
#define PER_T (NW / NTHREADS)   // 4

typedef unsigned long long u64;
typedef uint32_t u32;

__device__ __forceinline__ u32 rotl32(u32 v, u32 r) { return (v << r) | (v >> (32u - r)); }

// Threefry-2x32, 20 rounds, exactly as jax/_src/prng.py threefry2x32.
__device__ __forceinline__ void tf2x32(u32 k0, u32 k1, u32 x0, u32 x1, u32* o0, u32* o1) {
  u32 ks2 = k0 ^ k1 ^ 0x1BD11BDAu;
  x0 += k0; x1 += k1;
#define TFR(r0, r1, r2, r3)                      \
  x0 += x1; x1 = rotl32(x1, r0); x1 ^= x0;       \
  x0 += x1; x1 = rotl32(x1, r1); x1 ^= x0;       \
  x0 += x1; x1 = rotl32(x1, r2); x1 ^= x0;       \
  x0 += x1; x1 = rotl32(x1, r3); x1 ^= x0;
  TFR(13, 15, 26, 6)  x0 += k1;  x1 += ks2 + 1u;
  TFR(17, 29, 16, 24) x0 += ks2; x1 += k0 + 2u;
  TFR(13, 15, 26, 6)  x0 += k0;  x1 += k1 + 3u;
  TFR(17, 29, 16, 24) x0 += k1;  x1 += ks2 + 4u;
  TFR(13, 15, 26, 6)  x0 += ks2; x1 += k0 + 5u;
#undef TFR
  *o0 = x0; *o1 = x1;
}

// jax uniform [0,1): bitcast((bits>>9)|0x3f800000) - 1.0f
__device__ __forceinline__ float unif01(u32 bits) {
  return __uint_as_float((bits >> 9) | 0x3f800000u) - 1.0f;
}

// monotone float -> u32 sort key
__device__ __forceinline__ u32 fkey(float f) {
  u32 b = __float_as_uint(f);
  return b ^ ((b >> 31) ? 0xFFFFFFFFu : 0x80000000u);
}

__global__ __launch_bounds__(NTHREADS)
void mcmc_kernel(const float* __restrict__ bigram,
                 const float* __restrict__ startv,
                 const float* __restrict__ endv,
                 int* __restrict__ out) {
  __shared__ int    s_perm[NW];
  __shared__ float  s_logit[NW];
  __shared__ float  s_gath[NW];
  __shared__ float  s_redf[NWAVES];
  __shared__ u64    s_redu[NWAVES];
  __shared__ double s_redd[NWAVES];
  __shared__ float  s_m, s_Z, s_w;
  __shared__ int    s_pos, s_tm, s_np, s_acc;
  __shared__ u32    s_kcat0, s_kcat1, s_ku0, s_ku1;

  const int tid = threadIdx.x;
  const int lane = tid & 63;
  const int wid = tid >> 6;

  // init: identity permutation, w0 via sequential fp32 sum
  for (int i = tid; i < NW; i += NTHREADS) s_perm[i] = i;
  for (int j = tid; j < NW - 1; j += NTHREADS) s_gath[j] = bigram[(u64)j * NW + (j + 1)];
  __syncthreads();
  if (tid == 0) {
    float S = 0.0f;
    for (int j = 0; j < NW - 1; ++j) S += s_gath[j];
    S = S + startv[0];
    S = S + endv[NW - 1];
    s_w = S;
  }
  __syncthreads();

  for (int t = 0; t < NSTEPS; ++t) {
    // ---- phase 0: key derivation + removal position (thread 0) ----
    if (tid == 0) {
      u32 kt0, kt1;
      tf2x32(0u, 42u, 0u, (u32)t, &kt0, &kt1);        // keys[t] = split(key(42), 2559)[t]
      u32 kp0, kp1, kc0, kc1, ku0, ku1;
      tf2x32(kt0, kt1, 0u, 0u, &kp0, &kp1);            // k_pos
      tf2x32(kt0, kt1, 0u, 1u, &kc0, &kc1);            // k_cat
      tf2x32(kt0, kt1, 0u, 2u, &ku0, &ku1);            // k_u
      // randint(k_pos, (), 0, 4096): k1,k2 = split(k_pos); span=4096 (pow2) ->
      // multiplier = 2^32 % 4096 = 0 -> pos = random_bits(k2) & 4095
      u32 k2a, k2b, ra, rb;
      tf2x32(kp0, kp1, 0u, 1u, &k2a, &k2b);            // k2 = split(k_pos)[1]
      tf2x32(k2a, k2b, 0u, 0u, &ra, &rb);
      int pos = (int)((ra ^ rb) & (u32)(NW - 1));      // partitionable bits = w1 ^ w2
      s_pos = pos;
      s_tm = s_perm[pos];
      s_kcat0 = kc0; s_kcat1 = kc1; s_ku0 = ku0; s_ku1 = ku1;
    }
    __syncthreads();
    const int pos = s_pos, tm = s_tm;

    // ---- phase 1: insertion logits + max ----
    // perm2(j) = s_perm[j + (j>=pos)], j in [0, NW-2]
    float lmax = -3.402823466e+38f;
    for (int i = tid; i < NW; i += NTHREADS) {
      float li;
      if (i == 0) {
        int r = s_perm[(0 >= pos) ? 1 : 0];
        li = startv[tm] + bigram[(u64)tm * NW + r];                 // fl(start + right)
      } else if (i == NW - 1) {
        int l = s_perm[((NW - 2) >= pos) ? (NW - 1) : (NW - 2)];
        li = endv[tm] + bigram[(u64)l * NW + tm];                   // fl(end + left)
      } else {
        int l = s_perm[((i - 1) >= pos) ? i : (i - 1)];
        int r = s_perm[(i >= pos) ? (i + 1) : i];
        li = bigram[(u64)l * NW + tm] + bigram[(u64)tm * NW + r];   // fl(left + right)
      }
      s_logit[i] = li;
      lmax = fmaxf(lmax, li);
    }
    for (int o = 32; o > 0; o >>= 1) lmax = fmaxf(lmax, __shfl_down(lmax, o, 64));
    if (lane == 0) s_redf[wid] = lmax;
    __syncthreads();
    if (tid == 0) {
      float m = s_redf[0];
      for (int w = 1; w < NWAVES; ++w) m = fmaxf(m, s_redf[w]);
      s_m = m;
    }
    __syncthreads();
    const float m = s_m;

    // ---- phase 2: softmax denominator Z + gumbel argmax (categorical) ----
    double zacc = 0.0;
    u64 best = 0;
    const u32 kc0 = s_kcat0, kc1 = s_kcat1;
    for (int i = tid; i < NW; i += NTHREADS) {
      float li = s_logit[i];
      float ex = (float)exp((double)(li - m));
      zacc += (double)ex;
      u32 ba, bb;
      tf2x32(kc0, kc1, 0u, (u32)i, &ba, &bb);
      float u = unif01(ba ^ bb);                       // partitionable bits = w1 ^ w2
      if (u == 0.0f) u = 1.17549435e-38f;              // uniform(minval=tiny) collapse
      float t1 = (float)log((double)u);                // fl32(log u), u<1 -> t1<0
      float t2 = (float)log((double)(-t1));
      float g = -t2;                                   // gumbel = -log(-log(u))
      float sv = g + li;
      u64 key = ((u64)fkey(sv) << 32) | (u32)(NW - 1 - i);  // max val, then min index
      if (key > best) best = key;
    }
    for (int o = 32; o > 0; o >>= 1) {
      u64 w = __shfl_down(best, o, 64);
      if (w > best) best = w;
      zacc += __shfl_down(zacc, o, 64);
    }
    if (lane == 0) { s_redu[wid] = best; s_redd[wid] = zacc; }
    __syncthreads();
    if (tid == 0) {
      u64 b = s_redu[0]; double z = s_redd[0];
      for (int w = 1; w < NWAVES; ++w) {
        if (s_redu[w] > b) b = s_redu[w];
        z += s_redd[w];
      }
      s_np = NW - 1 - (int)(b & 0xFFFFFFFFu);
      s_Z = (float)z;
    }
    __syncthreads();
    const int np = s_np;

    // ---- phase 3: gather consecutive-pair bigram values of the proposed sample ----
    // sample(i) = i<np ? perm2(i) : (i==np ? tm : perm2(i-1))
    for (int j = tid; j < NW - 1; j += NTHREADS) {
      int a = (j < np) ? s_perm[j + (j >= pos)]
                       : ((j == np) ? tm : s_perm[(j - 1) + ((j - 1) >= pos)]);
      int j1 = j + 1;
      int b = (j1 < np) ? s_perm[j1 + (j1 >= pos)]
                        : ((j1 == np) ? tm : s_perm[(j1 - 1) + ((j1 - 1) >= pos)]);
      s_gath[j] = bigram[(u64)a * NW + b];
    }
    __syncthreads();

    // ---- phase 4: sequential fp32 fresh sum + MH accept (thread 0) ----
    if (tid == 0) {
      float S = 0.0f;
      for (int j = 0; j < NW - 1; ++j) S += s_gath[j];   // left-to-right, init 0
      int s0 = (0 < np) ? s_perm[(0 >= pos) ? 1 : 0] : tm;
      int sl = ((NW - 1) == np) ? tm : s_perm[(NW - 2) + ((NW - 2) >= pos)];
      S = S + startv[s0];
      S = S + endv[sl];
      float dw = S - s_w;
      float e1 = (float)exp((double)dw);
      float en = (float)exp((double)(s_logit[np] - m));
      float eo = (float)exp((double)(s_logit[pos] - m));
      float pn = en / s_Z;
      float po = eo / s_Z;
      float acc = e1 * pn;
      acc = acc / po;
      acc = fminf(1.0f, acc);
      u32 ua, ub;
      tf2x32(s_ku0, s_ku1, 0u, 0u, &ua, &ub);
      float u = unif01(ua ^ ub);                         // partitionable bits = w1 ^ w2
      int accept = (acc > u) ? 1 : 0;
      s_acc = accept;
      if (accept) s_w = S;
    }
    __syncthreads();

    // ---- phase 5: apply insertion to s_perm if accepted ----
    int stash[PER_T];
    if (s_acc) {
      for (int k = 0; k < PER_T; ++k) {
        int i = tid + k * NTHREADS;
        stash[k] = (i < np) ? s_perm[i + (i >= pos)]
                            : ((i == np) ? tm : s_perm[(i - 1) + ((i - 1) >= pos)]);
      }
    }
    __syncthreads();
    if (s_acc) {
      for (int k = 0; k < PER_T; ++k) {
        int i = tid + k * NTHREADS;
        s_perm[i] = stash[k];
      }
    }
    __syncthreads();

    // ---- phase 6: emit thinned sample (chain[t+1] for t+1 in {9,19,...,2559}) ----
    if (((t + 1) % 10) == 9) {
      int row = (t - 8) / 10;
      for (int i = tid; i < NW; i += NTHREADS) out[(u64)row * NW + i] = s_perm[i];
    }
    __syncthreads();
  }
}

extern "C" void kernel_launch(void* const* d_in, const int* in_sizes, int n_in,
                              void* d_out, int out_size, void* d_ws, size_t ws_size,
                              hipStream_t stream) {
  // inputs: [0] n_words (int, ignored - fixed 4096), [1] bigram f32[4096*4096],
  //         [2] start f32[4096], [3] end f32[4096]; out: int32[256*4096]
  const float* bigram = (const float*)d_in[1];
  const float* startv = (const float*)d_in[2];
  const float* endv   = (const float*)d_in[3];
  int* out = (int*)d_out;
  hipLaunchKernelGGL(mcmc_kernel, dim3(1), dim3(NTHREADS), 0, stream,
                     bigram, startv, endv, out);
}